// Round 6
// baseline (120.742 us; speedup 1.0000x reference)
//
#include <hip/hip_runtime.h>
#include <hip/hip_fp16.h>
#include <math.h>

#define NUM_ENT 14541
#define NUM_REL2 474
#define EMBED_D 200
#define BATCH 256
#define GAMMA 9.0f

#define TILE_B 64
#define TILE_N 128
#define ROWW (EMBED_D / 2)          // 100 uints per fp16 row
#define ROWQ (EMBED_D / 8)          // 25 uint4 (octs) per row
#define NOCTS ROWQ

#define ENT_OCTS (NUM_ENT * NOCTS)  // 363525
#define OBJ_OCTS (BATCH   * NOCTS)  // 6400

typedef _Float16 h2 __attribute__((ext_vector_type(2)));

__device__ __forceinline__ h2 habs2(h2 x) {
    unsigned u = __builtin_bit_cast(unsigned, x) & 0x7FFF7FFFu;
    return __builtin_bit_cast(h2, u);
}

// acc += sum_{8 dims} |ov - ev|  (v_pk_add_f16(neg) + v_and_b32 + v_dot2_f32_f16)
__device__ __forceinline__ float oct_l1(uint4 ov, uint4 ev, float acc, h2 ones) {
    h2 d;
    d = __builtin_bit_cast(h2, ov.x) - __builtin_bit_cast(h2, ev.x);
    acc = __builtin_amdgcn_fdot2(habs2(d), ones, acc, false);
    d = __builtin_bit_cast(h2, ov.y) - __builtin_bit_cast(h2, ev.y);
    acc = __builtin_amdgcn_fdot2(habs2(d), ones, acc, false);
    d = __builtin_bit_cast(h2, ov.z) - __builtin_bit_cast(h2, ev.z);
    acc = __builtin_amdgcn_fdot2(habs2(d), ones, acc, false);
    d = __builtin_bit_cast(h2, ov.w) - __builtin_bit_cast(h2, ev.w);
    acc = __builtin_amdgcn_fdot2(habs2(d), ones, acc, false);
    return acc;
}

// ---------------- prep: fp32 -> fp16 tables in d_ws ----------------
__global__ __launch_bounds__(256)
void prep_kernel(const float* __restrict__ ent, const float* __restrict__ relE,
                 const int* __restrict__ sub, const int* __restrict__ rel,
                 unsigned int* __restrict__ ent16, unsigned int* __restrict__ obj16)
{
    const int idx = blockIdx.x * 256 + threadIdx.x;
    if (idx < ENT_OCTS) {
        const int e = idx / NOCTS, o = idx - e * NOCTS;
        const float* p = ent + (size_t)e * EMBED_D + o * 8;
        const float4 a = *(const float4*)p;
        const float4 b = *(const float4*)(p + 4);
        uint4 v;
        v.x = __builtin_bit_cast(unsigned, __builtin_amdgcn_cvt_pkrtz(a.x, a.y));
        v.y = __builtin_bit_cast(unsigned, __builtin_amdgcn_cvt_pkrtz(a.z, a.w));
        v.z = __builtin_bit_cast(unsigned, __builtin_amdgcn_cvt_pkrtz(b.x, b.y));
        v.w = __builtin_bit_cast(unsigned, __builtin_amdgcn_cvt_pkrtz(b.z, b.w));
        *(uint4*)(ent16 + (size_t)idx * 4) = v;
    } else if (idx < ENT_OCTS + OBJ_OCTS) {
        const int k = idx - ENT_OCTS;
        const int bI = k / NOCTS, o = k - bI * NOCTS;
        const float* pa = ent  + (size_t)sub[bI] * EMBED_D + o * 8;
        const float* pr = relE + (size_t)rel[bI] * EMBED_D + o * 8;
        const float4 a0 = *(const float4*)pa;
        const float4 a1 = *(const float4*)(pa + 4);
        const float4 r0 = *(const float4*)pr;
        const float4 r1 = *(const float4*)(pr + 4);
        uint4 v;
        v.x = __builtin_bit_cast(unsigned, __builtin_amdgcn_cvt_pkrtz(a0.x + r0.x, a0.y + r0.y));
        v.y = __builtin_bit_cast(unsigned, __builtin_amdgcn_cvt_pkrtz(a0.z + r0.z, a0.w + r0.w));
        v.z = __builtin_bit_cast(unsigned, __builtin_amdgcn_cvt_pkrtz(a1.x + r1.x, a1.y + r1.y));
        v.w = __builtin_bit_cast(unsigned, __builtin_amdgcn_cvt_pkrtz(a1.z + r1.z, a1.w + r1.w));
        *(uint4*)(obj16 + (size_t)k * 4) = v;
    }
}

// ---------------- main ----------------
// 256 threads: tx = tid&15 (n), ty = tid>>4 (b); micro-tile 4(b) x 8(n).
// Both tiles staged fully in LDS with coalesced loads; ONE barrier total.
// Octs software-pipelined A/B through registers.
__device__ __forceinline__ void load_ev(uint4 (&ev)[8], const char* ebase, int boff) {
#pragma unroll
    for (int j = 0; j < 8; ++j)
        ev[j] = *(const uint4*)(ebase + j * (16 * ROWW * 4) + boff);
}

__device__ __forceinline__ void load_ov(uint4 (&ov)[4], const char* obase, int boff) {
#pragma unroll
    for (int i = 0; i < 4; ++i)
        ov[i] = *(const uint4*)(obase + i * (16 * ROWW * 4) + boff);
}

__device__ __forceinline__ void comp(float (&acc)[4][8], const uint4 (&ov)[4],
                                     const uint4 (&ev)[8], h2 ones) {
#pragma unroll
    for (int i = 0; i < 4; ++i)
#pragma unroll
        for (int j = 0; j < 8; ++j)
            acc[i][j] = oct_l1(ov[i], ev[j], acc[i][j], ones);
}

__global__ __launch_bounds__(256, 2)
void transe_main(const unsigned int* __restrict__ ent16,
                 const unsigned int* __restrict__ obj16,
                 float* __restrict__ out)
{
    __shared__ __align__(16) unsigned int entS[TILE_N * ROWW];   // 51200 B
    __shared__ __align__(16) unsigned int objS[TILE_B * ROWW];   // 25600 B

    const int tid   = threadIdx.x;
    const int nbase = blockIdx.x * TILE_N;
    const int bbase = blockIdx.y * TILE_B;

    // stage ent tile: 128 rows x 25 uint4 = 3200 items, per-row clamp
    for (int it = tid; it < TILE_N * ROWQ; it += 256) {
        const int row = it / ROWQ;
        const int oq  = it - row * ROWQ;
        int gr = nbase + row;
        if (gr >= NUM_ENT) gr = NUM_ENT - 1;   // dup row; stores guarded in epilogue
        *(uint4*)&entS[it * 4] = *(const uint4*)(ent16 + (size_t)gr * ROWW + oq * 4);
    }
    // stage obj tile: contiguous 1600 uint4
    for (int it = tid; it < TILE_B * ROWQ; it += 256)
        *(uint4*)&objS[it * 4] = *(const uint4*)(obj16 + (size_t)bbase * ROWW + it * 4);
    __syncthreads();

    const int tx = tid & 15, ty = tid >> 4;
    const char* ebase = (const char*)&entS[tx * ROWW];
    const char* obase = (const char*)&objS[ty * ROWW];

    float acc[4][8] = {};
    h2 ones; ones[0] = (_Float16)1.0f; ones[1] = (_Float16)1.0f;

    uint4 evA[8], ovA[4], evB[8], ovB[4];
    load_ev(evA, ebase, 0);
    load_ov(ovA, obase, 0);

    int boff = 0;
#pragma unroll 1
    for (int o = 0; o < NOCTS - 1; o += 2) {
        load_ev(evB, ebase, boff + 16);
        load_ov(ovB, obase, boff + 16);
        comp(acc, ovA, evA, ones);
        load_ev(evA, ebase, boff + 32);   // o+2 <= 24 (o max 22)
        load_ov(ovA, obase, boff + 32);
        comp(acc, ovB, evB, ones);
        boff += 32;
    }
    comp(acc, ovA, evA, ones);            // oct 24

    // epilogue: sigmoid(GAMMA - dist)
#pragma unroll
    for (int i = 0; i < 4; ++i) {
        const int b_g = bbase + ty + 16 * i;
#pragma unroll
        for (int j = 0; j < 8; ++j) {
            const int n_g = nbase + tx + 16 * j;
            if (n_g < NUM_ENT) {
                out[(size_t)b_g * NUM_ENT + n_g] =
                    1.0f / (1.0f + __expf(acc[i][j] - GAMMA));
            }
        }
    }
}

extern "C" void kernel_launch(void* const* d_in, const int* in_sizes, int n_in,
                              void* d_out, int out_size, void* d_ws, size_t ws_size,
                              hipStream_t stream) {
    const float* ent  = (const float*)d_in[0];
    const float* relE = (const float*)d_in[1];
    const int*   sub  = (const int*)d_in[2];
    const int*   rel  = (const int*)d_in[3];
    float* out = (float*)d_out;

    unsigned int* ent16 = (unsigned int*)d_ws;
    unsigned int* obj16 = ent16 + (size_t)ENT_OCTS * 4;

    const int prep_total = ENT_OCTS + OBJ_OCTS;
    prep_kernel<<<(prep_total + 255) / 256, 256, 0, stream>>>(ent, relE, sub, rel,
                                                              ent16, obj16);

    dim3 grid((NUM_ENT + TILE_N - 1) / TILE_N, BATCH / TILE_B);   // 114 x 4
    transe_main<<<grid, 256, 0, stream>>>(ent16, obj16, out);
}

// Round 7
// 84.767 us; speedup vs baseline: 1.4244x; 1.4244x over previous
//
#include <hip/hip_runtime.h>
#include <math.h>

#define NUM_ENT 14541
#define NUM_REL2 474
#define EMBED_D 200
#define BATCH 256
#define GAMMA 9.0f

#define TILE 64
#define ROWB 208                 // padded row bytes (200 data + 8 zero pad), 16B-aligned
#define ROWI 52                  // u32 per row
#define ROWQ 13                  // uint4 (16B chunks) per row
#define ENT_ROWS 14592           // 228 tiles * 64 (pad rows zero-filled)
#define ENT_ITEMS (ENT_ROWS * ROWI)   // 758784 u32 items
#define OBJ_ITEMS (BATCH * ROWI)      // 13312

// ---------------- prep: fp32 -> u8 quantized tables in d_ws ----------------
// q = clamp(round(x*8 + 128), 0, 255); pad cols/rows = 0 in BOTH tables
// (sad of pad bytes contributes |0-0| = 0).
__device__ __forceinline__ unsigned q8(float x) {
    float t = fmaf(x, 8.0f, 128.5f);           // +0.5 for round-down trunc
    t = fminf(fmaxf(t, 0.0f), 255.0f);
    return (unsigned)(int)t;
}
__device__ __forceinline__ unsigned pack4(float a, float b, float c, float d) {
    return q8(a) | (q8(b) << 8) | (q8(c) << 16) | (q8(d) << 24);
}

__global__ __launch_bounds__(256)
void prep_kernel(const float* __restrict__ ent, const float* __restrict__ relE,
                 const int* __restrict__ sub, const int* __restrict__ rel,
                 unsigned* __restrict__ ent8, unsigned* __restrict__ obj8)
{
    const int idx = blockIdx.x * 256 + threadIdx.x;
    if (idx < ENT_ITEMS) {
        const int row = idx / ROWI;
        const int c4  = (idx - row * ROWI) * 4;    // byte col of first of 4 dims
        unsigned q = 0u;
        if (row < NUM_ENT && c4 < EMBED_D) {
            const float4 v = *(const float4*)(ent + (size_t)row * EMBED_D + c4);
            q = pack4(v.x, v.y, v.z, v.w);
        }
        ent8[idx] = q;
    } else if (idx < ENT_ITEMS + OBJ_ITEMS) {
        const int k   = idx - ENT_ITEMS;
        const int row = k / ROWI;
        const int c4  = (k - row * ROWI) * 4;
        unsigned q = 0u;
        if (c4 < EMBED_D) {
            const float4 a = *(const float4*)(ent  + (size_t)sub[row] * EMBED_D + c4);
            const float4 r = *(const float4*)(relE + (size_t)rel[row] * EMBED_D + c4);
            q = pack4(a.x + r.x, a.y + r.y, a.z + r.z, a.w + r.w);
        }
        obj8[k] = q;
    }
}

// ---------------- main: u8 SAD L1 distance + sigmoid ----------------
// 256 threads: tx = tid&15 (n), ty = tid>>4 (b); micro-tile 4x4.
// Both 64-row tiles staged once in LDS (contiguous copy, one barrier).
// Core: v_sad_u8 = 4 dims + accumulate per instruction.
__global__ __launch_bounds__(256, 4)
void transe_main(const unsigned* __restrict__ ent8,
                 const unsigned* __restrict__ obj8,
                 float* __restrict__ out)
{
    __shared__ __align__(16) unsigned entS[TILE * ROWI];   // 13312 B
    __shared__ __align__(16) unsigned objS[TILE * ROWI];   // 13312 B

    const int tid   = threadIdx.x;
    const int nbase = blockIdx.x * TILE;
    const int bbase = blockIdx.y * TILE;

    // stage both tiles: straight contiguous uint4 copies (832 each)
    const uint4* eg = (const uint4*)(ent8 + (size_t)nbase * ROWI);
    const uint4* og = (const uint4*)(obj8 + (size_t)bbase * ROWI);
    uint4* esh = (uint4*)entS;
    uint4* osh = (uint4*)objS;
    for (int it = tid; it < TILE * ROWQ; it += 256) {
        esh[it] = eg[it];
        osh[it] = og[it];
    }
    __syncthreads();

    const int tx = tid & 15, ty = tid >> 4;

    unsigned acc[4][4] = {};

#pragma unroll 1
    for (int c = 0; c < ROWQ; ++c) {
        uint4 ev[4], ov[4];
#pragma unroll
        for (int j = 0; j < 4; ++j)
            ev[j] = esh[(tx + 16 * j) * ROWQ + c];
#pragma unroll
        for (int i = 0; i < 4; ++i)
            ov[i] = osh[(ty + 16 * i) * ROWQ + c];

#pragma unroll
        for (int i = 0; i < 4; ++i) {
#pragma unroll
            for (int j = 0; j < 4; ++j) {
                unsigned a = acc[i][j];
                a = __builtin_amdgcn_sad_u8(ov[i].x, ev[j].x, a);
                a = __builtin_amdgcn_sad_u8(ov[i].y, ev[j].y, a);
                a = __builtin_amdgcn_sad_u8(ov[i].z, ev[j].z, a);
                a = __builtin_amdgcn_sad_u8(ov[i].w, ev[j].w, a);
                acc[i][j] = a;
            }
        }
    }

    // epilogue: dist = sad/8 ; score = sigmoid(GAMMA - dist)
#pragma unroll
    for (int i = 0; i < 4; ++i) {
        const int b_g = bbase + ty + 16 * i;
#pragma unroll
        for (int j = 0; j < 4; ++j) {
            const int n_g = nbase + tx + 16 * j;
            if (n_g < NUM_ENT) {
                const float dist = (float)acc[i][j] * 0.125f;
                out[(size_t)b_g * NUM_ENT + n_g] =
                    1.0f / (1.0f + __expf(dist - GAMMA));
            }
        }
    }
}

extern "C" void kernel_launch(void* const* d_in, const int* in_sizes, int n_in,
                              void* d_out, int out_size, void* d_ws, size_t ws_size,
                              hipStream_t stream) {
    const float* ent  = (const float*)d_in[0];
    const float* relE = (const float*)d_in[1];
    const int*   sub  = (const int*)d_in[2];
    const int*   rel  = (const int*)d_in[3];
    float* out = (float*)d_out;

    unsigned* ent8 = (unsigned*)d_ws;
    unsigned* obj8 = ent8 + ENT_ITEMS;     // 3,035,136 B offset; total ws ~3.1 MB

    const int prep_total = ENT_ITEMS + OBJ_ITEMS;
    prep_kernel<<<(prep_total + 255) / 256, 256, 0, stream>>>(ent, relE, sub, rel,
                                                              ent8, obj8);

    dim3 grid(ENT_ROWS / TILE, BATCH / TILE);   // 228 x 4
    transe_main<<<grid, 256, 0, stream>>>(ent8, obj8, out);
}